// Round 1
// baseline (244.524 us; speedup 1.0000x reference)
//
#include <hip/hip_runtime.h>
#include <math.h>

// AdjustNet: B=32, L=512, C=256, N=16
//  stage1: t1[b,c,j] = gelu(LN_128(query^T @ w1 + b1))          (K1)
//  stage2: q[b,l,c]  = t1 @ w2 + b2                              (K2)
//  stage3: adj = tanh(gelu(LN_256(q@w3+b3)) @ w4 + b4)*0.02 ->
//          pos = tanh(offset+adj+ref), write pos + offset copy   (K3)
//  stage4: out[b,l,n,:] = w0*x[b,c0,:] + w1*x[b,c1,:]            (K4)

#define B_  32
#define L_  512
#define C_  256
#define N_  16
#define L4_ 128

__device__ __forceinline__ float gelu_exact(float v) {
    return 0.5f * v * (1.0f + erff(v * 0.70710678118654752f));
}

// ---------------------------------------------------------------- K1
// grid: B * (C/32) = 256 blocks, 256 threads.
// block computes tile [32 c][128 j]; thread (cg,j) holds 16 c-rows.
__global__ __launch_bounds__(256) void k1_gemm1(
    const float* __restrict__ query, const float* __restrict__ w1,
    const float* __restrict__ b1, const float* __restrict__ g1,
    const float* __restrict__ bt1, float* __restrict__ t1) {
  __shared__ float As[32][36];    // [l][c], pad 36 keeps float4 align
  __shared__ float Ws[32][128];   // [l][j]
  __shared__ float Hs[32][132];   // [c][j] pre-LN
  const int b  = blockIdx.x >> 3;
  const int c0 = (blockIdx.x & 7) << 5;
  const int tid = threadIdx.x;
  const int j  = tid & 127;
  const int cg = tid >> 7;

  float acc[16];
#pragma unroll
  for (int i = 0; i < 16; ++i) acc[i] = 0.f;

  for (int kc = 0; kc < 16; ++kc) {
    const int l0 = kc << 5;
    for (int idx = tid; idx < 1024; idx += 256) {
      int li = idx >> 5, ci = idx & 31;
      As[li][ci] = query[((b * L_) + l0 + li) * C_ + c0 + ci];
    }
    for (int idx = tid; idx < 4096; idx += 256) {
      int li = idx >> 7, ji = idx & 127;
      Ws[li][ji] = w1[(l0 + li) * L4_ + ji];
    }
    __syncthreads();
#pragma unroll
    for (int li = 0; li < 32; ++li) {
      float wv = Ws[li][j];
      const float4* ar = (const float4*)&As[li][cg * 16];
      float4 a0 = ar[0], a1 = ar[1], a2 = ar[2], a3 = ar[3];
      acc[0]  += a0.x * wv; acc[1]  += a0.y * wv; acc[2]  += a0.z * wv; acc[3]  += a0.w * wv;
      acc[4]  += a1.x * wv; acc[5]  += a1.y * wv; acc[6]  += a1.z * wv; acc[7]  += a1.w * wv;
      acc[8]  += a2.x * wv; acc[9]  += a2.y * wv; acc[10] += a2.z * wv; acc[11] += a2.w * wv;
      acc[12] += a3.x * wv; acc[13] += a3.y * wv; acc[14] += a3.z * wv; acc[15] += a3.w * wv;
    }
    __syncthreads();
  }
  const float b1j = b1[j];
#pragma unroll
  for (int i = 0; i < 16; ++i) Hs[cg * 16 + i][j] = acc[i] + b1j;
  __syncthreads();

  // LayerNorm over j (D=128): 8 lanes per row, contiguous in wave
  const int r = tid >> 3, g = tid & 7;
  const float* hrow = &Hs[r][g * 16];
  float s = 0.f, s2 = 0.f;
#pragma unroll
  for (int jj = 0; jj < 16; ++jj) { float v = hrow[jj]; s += v; s2 += v * v; }
#pragma unroll
  for (int m = 1; m < 8; m <<= 1) { s += __shfl_xor(s, m, 64); s2 += __shfl_xor(s2, m, 64); }
  const float mean = s * (1.f / 128.f);
  float var = s2 * (1.f / 128.f) - mean * mean;
  var = fmaxf(var, 0.f);
  const float rstd = rsqrtf(var + 1e-12f);
  float* orow = &t1[((b * C_) + c0 + r) * L4_ + g * 16];
#pragma unroll
  for (int jj = 0; jj < 16; ++jj) {
    int jn = g * 16 + jj;
    float v = (hrow[jj] - mean) * rstd * g1[jn] + bt1[jn];
    orow[jj] = gelu_exact(v);
  }
}

// ---------------------------------------------------------------- K2
// q[b,l,c] = sum_j t1[b,c,j]*w2[j,l] + b2[l]
// grid: B*(L/64)*(C/64)=1024 blocks, 256 thr, 4x4 register tile.
__global__ __launch_bounds__(256) void k2_gemm2(
    const float* __restrict__ t1, const float* __restrict__ w2,
    const float* __restrict__ b2, float* __restrict__ qout) {
  __shared__ float w2s[32][68];   // [j][l]
  __shared__ float t1s[32][68];   // [j][c]
  const int b  = blockIdx.x >> 5;
  const int rr = blockIdx.x & 31;
  const int l0 = (rr >> 2) << 6;
  const int c0 = (rr & 3) << 6;
  const int tid = threadIdx.x;
  const int tx = tid & 15, ty = tid >> 4;

  float acc[4][4];
#pragma unroll
  for (int i = 0; i < 4; ++i)
#pragma unroll
    for (int k = 0; k < 4; ++k) acc[i][k] = 0.f;

  for (int jc = 0; jc < 4; ++jc) {
    const int j0 = jc << 5;
    for (int idx = tid; idx < 2048; idx += 256) {
      int jj = idx >> 6, ll = idx & 63;
      w2s[jj][ll] = w2[(j0 + jj) * L_ + l0 + ll];
    }
    for (int idx = tid; idx < 2048; idx += 256) {
      int jj = idx & 31, cc = idx >> 5;
      t1s[jj][cc] = t1[((b * C_) + c0 + cc) * L4_ + j0 + jj];
    }
    __syncthreads();
#pragma unroll
    for (int jj = 0; jj < 32; ++jj) {
      float4 av = *(const float4*)&w2s[jj][ty * 4];
      float4 bv = *(const float4*)&t1s[jj][tx * 4];
      float avv[4] = {av.x, av.y, av.z, av.w};
      float bvv[4] = {bv.x, bv.y, bv.z, bv.w};
#pragma unroll
      for (int i = 0; i < 4; ++i)
#pragma unroll
        for (int k = 0; k < 4; ++k) acc[i][k] += avv[i] * bvv[k];
    }
    __syncthreads();
  }
#pragma unroll
  for (int i = 0; i < 4; ++i) {
    int l = l0 + ty * 4 + i;
    float bb = b2[l];
    float4 o = make_float4(acc[i][0] + bb, acc[i][1] + bb, acc[i][2] + bb, acc[i][3] + bb);
    *(float4*)&qout[((b * L_) + l) * C_ + c0 + tx * 4] = o;
  }
}

// ---------------------------------------------------------------- K3
// per (b, 16 l-rows): h3 = q@w3+b3, LN_256, gelu, @w4+b4, tanh*0.02,
// combine with offset -> pos; write pos + offset copy.
__global__ __launch_bounds__(256) void k3_adjust(
    const float* __restrict__ qbuf, const float* __restrict__ w3,
    const float* __restrict__ b3, const float* __restrict__ g3,
    const float* __restrict__ bt3, const float* __restrict__ w4,
    const float* __restrict__ b4, const float* __restrict__ offset,
    float* __restrict__ off_out, float* __restrict__ pos_out) {
  __shared__ float qs[256][20];    // [c][r], pad 20 (80B) float4-aligned
  __shared__ float hs[16][264];    // [r][k]
  __shared__ float ts[16][264];    // [r][k] post-gelu
  const int b  = blockIdx.x >> 5;
  const int l0 = (blockIdx.x & 31) << 4;
  const int tid = threadIdx.x;

  for (int idx = tid; idx < 4096; idx += 256) {
    int c = idx & 255, r = idx >> 8;
    qs[c][r] = qbuf[((b * L_) + l0 + r) * C_ + c];
  }
  __syncthreads();

  // GEMM3: thread = output channel k, 16 rows
  const int k = tid;
  float accr[16];
#pragma unroll
  for (int i = 0; i < 16; ++i) accr[i] = 0.f;
  for (int c = 0; c < 256; ++c) {
    float wv = w3[c * C_ + k];
    const float4* qr = (const float4*)&qs[c][0];
    float4 q0 = qr[0], q1 = qr[1], q2 = qr[2], q3 = qr[3];
    accr[0]  += q0.x * wv; accr[1]  += q0.y * wv; accr[2]  += q0.z * wv; accr[3]  += q0.w * wv;
    accr[4]  += q1.x * wv; accr[5]  += q1.y * wv; accr[6]  += q1.z * wv; accr[7]  += q1.w * wv;
    accr[8]  += q2.x * wv; accr[9]  += q2.y * wv; accr[10] += q2.z * wv; accr[11] += q2.w * wv;
    accr[12] += q3.x * wv; accr[13] += q3.y * wv; accr[14] += q3.z * wv; accr[15] += q3.w * wv;
  }
  const float b3k = b3[k];
#pragma unroll
  for (int r = 0; r < 16; ++r) hs[r][k] = accr[r] + b3k;
  __syncthreads();

  // LayerNorm over k (D=256): 16 lanes per row
  const int r = tid >> 4, g = tid & 15;
  {
    const float* hrow = &hs[r][g * 16];
    float s = 0.f, s2 = 0.f;
#pragma unroll
    for (int jj = 0; jj < 16; ++jj) { float v = hrow[jj]; s += v; s2 += v * v; }
#pragma unroll
    for (int m = 1; m < 16; m <<= 1) { s += __shfl_xor(s, m, 64); s2 += __shfl_xor(s2, m, 64); }
    const float mean = s * (1.f / 256.f);
    float var = s2 * (1.f / 256.f) - mean * mean;
    var = fmaxf(var, 0.f);
    const float rstd = rsqrtf(var + 1e-12f);
#pragma unroll
    for (int jj = 0; jj < 16; ++jj) {
      int kk = g * 16 + jj;
      float v = (hrow[jj] - mean) * rstd * g3[kk] + bt3[kk];
      ts[r][kk] = gelu_exact(v);
    }
  }
  __syncthreads();

  // GEMM4: thread (r, n) computes adj pair; then pos
  const int n = g;
  float a0 = 0.f, a1 = 0.f;
  for (int kk = 0; kk < 256; ++kk) {
    float tv = ts[r][kk];
    float2 wv = *(const float2*)&w4[kk * 32 + 2 * n];
    a0 += tv * wv.x;
    a1 += tv * wv.y;
  }
  const float adj0 = tanhf(a0 + b4[2 * n]) * 0.02f;
  const float adj1 = tanhf(a1 + b4[2 * n + 1]) * 0.02f;
  const int l = l0 + r;
  const float2 offv = *(const float2*)&offset[((b * L_) + l) * 32 + 2 * n];
  const float pos0 = tanhf(offv.x + adj0);
  const float ref_y = ((float)n + 0.5f) * 2.0f * ((float)l + 1e-9f) * (1.0f / 8192.0f) - 1.0f;
  const float pos1 = tanhf(offv.y + adj1 + ref_y);
  *(float2*)&off_out[((b * L_) + l) * 32 + 2 * n] = offv;
  *(float2*)&pos_out[(((b * L_) + l) * 16 + n) * 2] = make_float2(pos0, pos1);
}

// ---------------------------------------------------------------- K4
// out[b,l,n,:] = w0*x[b,c0,:] + w1*x[b,c1,:]; taps recomputed from pos
__global__ __launch_bounds__(256) void k4_gather(
    const float* __restrict__ x, const float* __restrict__ pos,
    float* __restrict__ outbuf) {
  const unsigned u = blockIdx.x * 256u + threadIdx.x;  // < 16,777,216 float4 units
  const unsigned t_idx = u >> 6;   // (b,l,n)
  const unsigned cj = u & 63;
  const int b = t_idx >> 13;
  const int l = (t_idx >> 4) & 511;
  const float pos1 = pos[t_idx * 2 + 1];
  const float pix = (pos1 + 1.0f) * 0.5f * 511.0f;
  const float i0f = floorf(pix);
  const int i0 = (int)i0f;
  const float frac = pix - i0f;
  const int i1 = i0 + 1;
  const bool v0 = (i0 >= 0) && (i0 < 512) && (i0 <= l);
  const bool v1 = (i1 >= 0) && (i1 < 512) && (i1 <= l);
  const int c0 = i0 < 0 ? 0 : (i0 > 511 ? 511 : i0);
  const int c1 = i1 < 0 ? 0 : (i1 > 511 ? 511 : i1);
  const float w0  = v0 ? (1.0f - frac) : 0.0f;
  const float w1v = v1 ? frac : 0.0f;
  const float4* x4 = (const float4*)x;
  const float4 va = x4[(unsigned)((b << 9) + c0) * 64u + cj];
  const float4 vb = x4[(unsigned)((b << 9) + c1) * 64u + cj];
  float4 o;
  o.x = w0 * va.x + w1v * vb.x;
  o.y = w0 * va.y + w1v * vb.y;
  o.z = w0 * va.z + w1v * vb.z;
  o.w = w0 * va.w + w1v * vb.w;
  ((float4*)outbuf)[u] = o;
}

extern "C" void kernel_launch(void* const* d_in, const int* in_sizes, int n_in,
                              void* d_out, int out_size, void* d_ws, size_t ws_size,
                              hipStream_t stream) {
  const float* query  = (const float*)d_in[0];
  const float* x      = (const float*)d_in[1];
  const float* offset = (const float*)d_in[2];
  const float* w1  = (const float*)d_in[3];
  const float* b1  = (const float*)d_in[4];
  const float* g1  = (const float*)d_in[5];
  const float* bt1 = (const float*)d_in[6];
  const float* w2  = (const float*)d_in[7];
  const float* b2  = (const float*)d_in[8];
  const float* w3  = (const float*)d_in[9];
  const float* b3  = (const float*)d_in[10];
  const float* g3  = (const float*)d_in[11];
  const float* bt3 = (const float*)d_in[12];
  const float* w4  = (const float*)d_in[13];
  const float* b4  = (const float*)d_in[14];

  float* out     = (float*)d_out;                    // [B,L,N,C] = 67,108,864
  float* off_out = out + 67108864;                   // [B,L,2N]  =    524,288
  float* pos_out = off_out + 524288;                 // [B,L,N,2] =    524,288

  float* t1 = (float*)d_ws;                          // [B,C,128] = 1,048,576 f
  float* q  = t1 + 1048576;                          // [B,L,C]   = 4,194,304 f

  k1_gemm1<<<256, 256, 0, stream>>>(query, w1, b1, g1, bt1, t1);
  k2_gemm2<<<1024, 256, 0, stream>>>(t1, w2, b2, q);
  k3_adjust<<<1024, 256, 0, stream>>>(q, w3, b3, g3, bt3, w4, b4, offset,
                                      off_out, pos_out);
  k4_gather<<<65536, 256, 0, stream>>>(x, pos_out, out);
}

// Round 2
// 121.836 us; speedup vs baseline: 2.0070x; 2.0070x over previous
//
#include <hip/hip_runtime.h>
#include <hip/hip_fp16.h>
#include <math.h>

// AdjustNet: B=32, L=512, C=256, N=16 — f16 MFMA pipeline
//  K0: transpose+cast weights -> w1T[128][512], w2T[512][128], w3T[256][256], w4T[32][256] (f16)
//  K1: t1[b,c,j] = gelu(LN_128(query^T @ w1 + b1))   (MFMA, M=16c N=128j K=512l)
//  K2: q[b,l,c]  = t1 @ w2 + b2                      (MFMA, M=64l N=64c K=128j)
//  K3: h=q@w3+b3, LN_256, gelu -> ts; a=ts@w4+b4 (MFMA); tanh*0.02; pos epilogue
//  K4: out[b,l,n,:] = w0*x[b,c0,:] + w1*x[b,c1,:]

typedef _Float16 f16;
typedef _Float16 f16x8 __attribute__((ext_vector_type(8)));
typedef float f32x4 __attribute__((ext_vector_type(4)));

#define ZERO4 f32x4{0.f, 0.f, 0.f, 0.f}

__device__ __forceinline__ float gelu_exact(float v) {
  return 0.5f * v * (1.0f + erff(v * 0.70710678118654752f));
}

// ---------------------------------------------------------------- K0
// generic 64x64 transpose-cast: in f32 [R][Cc] -> out f16 [Cc][R]
__global__ __launch_bounds__(256) void k0_prep(
    const float* __restrict__ w1, const float* __restrict__ w2,
    const float* __restrict__ w3, const float* __restrict__ w4,
    f16* __restrict__ w1T, f16* __restrict__ w2T,
    f16* __restrict__ w3T, f16* __restrict__ w4T) {
  __shared__ f16 tile[64][80];
  int blk = blockIdx.x;
  const float* in; f16* out; int R, Cc, tr, tc;
  if (blk < 16)      { in = w1; out = w1T; R = 512; Cc = 128; tr = blk >> 1; tc = blk & 1; }
  else if (blk < 32) { blk -= 16; in = w2; out = w2T; R = 128; Cc = 512; tr = blk >> 3; tc = blk & 7; }
  else if (blk < 48) { blk -= 32; in = w3; out = w3T; R = 256; Cc = 256; tr = blk >> 2; tc = blk & 3; }
  else               { blk -= 48; in = w4; out = w4T; R = 256; Cc = 32;  tr = blk;      tc = 0; }
  const int r0 = tr * 64, c0 = tc * 64;
  const int tid = threadIdx.x;
  for (int id = tid; id < 4096; id += 256) {
    int rr = id >> 6, cc = id & 63;
    if (c0 + cc < Cc) tile[cc][rr] = (f16)in[(r0 + rr) * Cc + c0 + cc];
  }
  __syncthreads();
  for (int id = tid; id < 512; id += 256) {
    int cc = id >> 3, ch = id & 7;
    if (c0 + cc < Cc)
      *(f16x8*)(out + (c0 + cc) * R + r0 + ch * 8) = *(f16x8*)&tile[cc][ch * 8];
  }
}

// ---------------------------------------------------------------- K1
// grid 512: b = blk>>4, c0 = (blk&15)*16. M=16 c, N=128 j, K=512 l (8 steps of 64)
__global__ __launch_bounds__(256) void k1_gemm1(
    const float* __restrict__ query, const f16* __restrict__ w1T,
    const float* __restrict__ b1, const float* __restrict__ g1,
    const float* __restrict__ bt1, f16* __restrict__ t1) {
  __shared__ char At[16 * 128];    // [16 c][64 l f16], 128B rows, XOR swizzled
  __shared__ char Bt[128 * 128];   // [128 j][64 l f16]
  __shared__ float hs[16][132];
  const int tid = threadIdx.x;
  const int b = blockIdx.x >> 4;
  const int c0 = (blockIdx.x & 15) << 4;
  const int lane = tid & 63, w = tid >> 6;
  const int mrow = lane & 15, kg = lane >> 4;

  f32x4 acc[2] = {ZERO4, ZERO4};
  for (int s = 0; s < 8; ++s) {
    const int k0 = s << 6;
    // stage A (transpose query tile): query[b][k0+k][c0+r] -> At[r][k]
    for (int id = tid; id < 1024; id += 256) {
      int k = id >> 4, r = id & 15;
      float v = query[((b << 9) + k0 + k) * 256 + c0 + r];
      *(f16*)(At + r * 128 + ((k << 1) ^ ((r & 7) << 4))) = (f16)v;
    }
    // stage B: w1T rows (j), 8 chunks of 16B each
    for (int id = tid; id < 1024; id += 256) {
      int rj = id >> 3, c = id & 7;
      f16x8 v = *(const f16x8*)(w1T + rj * 512 + k0 + c * 8);
      *(f16x8*)(Bt + rj * 128 + ((c * 16) ^ ((rj & 7) << 4))) = v;
    }
    __syncthreads();
#pragma unroll
    for (int kk = 0; kk < 2; ++kk) {
      f16x8 a = *(const f16x8*)(At + mrow * 128 + (((kk << 6) + (kg << 4)) ^ ((mrow & 7) << 4)));
#pragma unroll
      for (int nf = 0; nf < 2; ++nf) {
        int rn = w * 32 + nf * 16 + mrow;
        f16x8 bfr = *(const f16x8*)(Bt + rn * 128 + (((kk << 6) + (kg << 4)) ^ ((rn & 7) << 4)));
        acc[nf] = __builtin_amdgcn_mfma_f32_16x16x32_f16(a, bfr, acc[nf], 0, 0, 0);
      }
    }
    __syncthreads();
  }
  // dump D (row = kg*4+i, col = lane&15 within n-frag)
#pragma unroll
  for (int nf = 0; nf < 2; ++nf)
#pragma unroll
    for (int i = 0; i < 4; ++i)
      hs[kg * 4 + i][w * 32 + nf * 16 + mrow] = acc[nf][i];
  __syncthreads();
  // LN over 128, 16 rows: 16 threads/row, 8 elems each
  const int r = tid >> 4, g = tid & 15;
  float s1 = 0.f, s2 = 0.f, vals[8];
#pragma unroll
  for (int jj = 0; jj < 8; ++jj) {
    int j = g * 8 + jj;
    float v = hs[r][j] + b1[j];
    vals[jj] = v; s1 += v; s2 += v * v;
  }
#pragma unroll
  for (int m = 1; m < 16; m <<= 1) { s1 += __shfl_xor(s1, m, 64); s2 += __shfl_xor(s2, m, 64); }
  const float mean = s1 * (1.f / 128.f);
  float var = fmaxf(s2 * (1.f / 128.f) - mean * mean, 0.f);
  const float rstd = rsqrtf(var + 1e-12f);
  f16 ov[8];
#pragma unroll
  for (int jj = 0; jj < 8; ++jj) {
    int j = g * 8 + jj;
    float v = (vals[jj] - mean) * rstd * g1[j] + bt1[j];
    ov[jj] = (f16)gelu_exact(v);
  }
  *(f16x8*)(t1 + ((b << 8) + c0 + r) * 128 + g * 8) = *(f16x8*)ov;
}

// ---------------------------------------------------------------- K2
// grid 1024: b=blk>>5, l0=((blk>>2)&7)*64, c0=(blk&3)*64. M=64 l, N=64 c, K=128 j
__global__ __launch_bounds__(256) void k2_gemm2(
    const f16* __restrict__ w2T, const f16* __restrict__ t1,
    const float* __restrict__ b2, f16* __restrict__ qout) {
  __shared__ char At[64 * 128];   // [64 l][64 j]
  __shared__ char Bt[64 * 128];   // [64 c][64 j]
  const int tid = threadIdx.x;
  const int b = blockIdx.x >> 5;
  const int l0 = ((blockIdx.x >> 2) & 7) << 6;
  const int c0 = (blockIdx.x & 3) << 6;
  const int lane = tid & 63, w = tid >> 6;
  const int mh = w >> 1, nh = w & 1;
  const int mrow = lane & 15, kg = lane >> 4;

  f32x4 acc[2][2] = {{ZERO4, ZERO4}, {ZERO4, ZERO4}};
  for (int s = 0; s < 2; ++s) {
    const int k0 = s << 6;
    for (int id = tid; id < 512; id += 256) {
      int r = id >> 3, c = id & 7;
      f16x8 v = *(const f16x8*)(w2T + (l0 + r) * 128 + k0 + c * 8);
      *(f16x8*)(At + r * 128 + ((c * 16) ^ ((r & 7) << 4))) = v;
    }
    for (int id = tid; id < 512; id += 256) {
      int r = id >> 3, c = id & 7;
      f16x8 v = *(const f16x8*)(t1 + ((b << 8) + c0 + r) * 128 + k0 + c * 8);
      *(f16x8*)(Bt + r * 128 + ((c * 16) ^ ((r & 7) << 4))) = v;
    }
    __syncthreads();
#pragma unroll
    for (int kk = 0; kk < 2; ++kk) {
      f16x8 a[2], bb[2];
#pragma unroll
      for (int mf = 0; mf < 2; ++mf) {
        int rm = mh * 32 + mf * 16 + mrow;
        a[mf] = *(const f16x8*)(At + rm * 128 + (((kk << 6) + (kg << 4)) ^ ((rm & 7) << 4)));
      }
#pragma unroll
      for (int nf = 0; nf < 2; ++nf) {
        int rn = nh * 32 + nf * 16 + mrow;
        bb[nf] = *(const f16x8*)(Bt + rn * 128 + (((kk << 6) + (kg << 4)) ^ ((rn & 7) << 4)));
      }
#pragma unroll
      for (int mf = 0; mf < 2; ++mf)
#pragma unroll
        for (int nf = 0; nf < 2; ++nf)
          acc[mf][nf] = __builtin_amdgcn_mfma_f32_16x16x32_f16(a[mf], bb[nf], acc[mf][nf], 0, 0, 0);
    }
    __syncthreads();
  }
#pragma unroll
  for (int mf = 0; mf < 2; ++mf) {
#pragma unroll
    for (int i = 0; i < 4; ++i) {
      int l = l0 + mh * 32 + mf * 16 + kg * 4 + i;
      float bb2 = b2[l];
#pragma unroll
      for (int nf = 0; nf < 2; ++nf)
        qout[((b << 9) + l) * 256 + c0 + nh * 32 + nf * 16 + mrow] = (f16)(acc[mf][nf][i] + bb2);
    }
  }
}

// ---------------------------------------------------------------- K3
// grid 512: b=blk>>4, l0=(blk&15)*32. GEMM3 M=32 l, N=256 k, K=256 c; LN; GEMM4 MFMA; epilogue
__global__ __launch_bounds__(256) void k3_adjust(
    const f16* __restrict__ qbuf, const f16* __restrict__ w3T,
    const float* __restrict__ b3, const float* __restrict__ g3,
    const float* __restrict__ bt3, const f16* __restrict__ w4T,
    const float* __restrict__ b4, const float* __restrict__ offset,
    float* __restrict__ off_out, float* __restrict__ pos_out) {
  __shared__ char pool[50176];     // ph1: At 4KB + Bt 32KB ; ph2: hs 33792B + ts 16384B
  __shared__ char w4t[32 * 512];   // [32 n][256 k f16] swizzled
  __shared__ float sb3[256];
  const int tid = threadIdx.x;
  const int b = blockIdx.x >> 4;
  const int l0 = (blockIdx.x & 15) << 5;
  const int lane = tid & 63, w = tid >> 6;
  const int mh = w & 1, nh = w >> 1;
  const int mrow = lane & 15, kg = lane >> 4;
  char* At = pool;
  char* Bt = pool + 4096;

  // one-time: w4 tile + b3 into LDS
  for (int id = tid; id < 1024; id += 256) {
    int r = id >> 5, c = id & 31;
    f16x8 v = *(const f16x8*)(w4T + r * 256 + c * 8);
    *(f16x8*)(w4t + r * 512 + ((c * 16) ^ ((r & 7) << 4))) = v;
  }
  sb3[tid] = b3[tid];

  f32x4 acc[8] = {ZERO4, ZERO4, ZERO4, ZERO4, ZERO4, ZERO4, ZERO4, ZERO4};
  for (int s = 0; s < 4; ++s) {
    const int k0 = s << 6;
    {  // At: 32 rows x 8 chunks = 256
      int r = tid >> 3, c = tid & 7;
      f16x8 v = *(const f16x8*)(qbuf + ((b << 9) + l0 + r) * 256 + k0 + c * 8);
      *(f16x8*)(At + r * 128 + ((c * 16) ^ ((r & 7) << 4))) = v;
    }
    for (int id = tid; id < 2048; id += 256) {  // Bt: 256 rows x 8 chunks
      int r = id >> 3, c = id & 7;
      f16x8 v = *(const f16x8*)(w3T + r * 256 + k0 + c * 8);
      *(f16x8*)(Bt + r * 128 + ((c * 16) ^ ((r & 7) << 4))) = v;
    }
    __syncthreads();
#pragma unroll
    for (int kk = 0; kk < 2; ++kk) {
      int arow = mh * 16 + mrow;
      f16x8 a = *(const f16x8*)(At + arow * 128 + (((kk << 6) + (kg << 4)) ^ ((arow & 7) << 4)));
#pragma unroll
      for (int nf = 0; nf < 8; ++nf) {
        int rn = nh * 128 + nf * 16 + mrow;
        f16x8 bfr = *(const f16x8*)(Bt + rn * 128 + (((kk << 6) + (kg << 4)) ^ ((rn & 7) << 4)));
        acc[nf] = __builtin_amdgcn_mfma_f32_16x16x32_f16(a, bfr, acc[nf], 0, 0, 0);
      }
    }
    __syncthreads();
  }
  // phase 2 overlay
  float (*hs)[264] = (float(*)[264])pool;   // [32][264] f32
  char* ts = pool + 33792;                  // [32][256 f16] swizzled, 512B rows
#pragma unroll
  for (int nf = 0; nf < 8; ++nf) {
    int col = nh * 128 + nf * 16 + mrow;
    float bias = sb3[col];
#pragma unroll
    for (int i = 0; i < 4; ++i)
      hs[mh * 16 + kg * 4 + i][col] = acc[nf][i] + bias;
  }
  __syncthreads();
  // LN over 256, 32 rows: 2 passes, 16 threads/row, 16 elems each
  for (int p = 0; p < 2; ++p) {
    const int r = p * 16 + (tid >> 4), g = tid & 15;
    float s1 = 0.f, s2 = 0.f, vals[16];
#pragma unroll
    for (int jj = 0; jj < 16; ++jj) {
      float v = hs[r][g * 16 + jj];
      vals[jj] = v; s1 += v; s2 += v * v;
    }
#pragma unroll
    for (int m = 1; m < 16; m <<= 1) { s1 += __shfl_xor(s1, m, 64); s2 += __shfl_xor(s2, m, 64); }
    const float mean = s1 * (1.f / 256.f);
    float var = fmaxf(s2 * (1.f / 256.f) - mean * mean, 0.f);
    const float rstd = rsqrtf(var + 1e-12f);
    f16 ov[16];
#pragma unroll
    for (int jj = 0; jj < 16; ++jj) {
      int kch = g * 16 + jj;
      float v = (vals[jj] - mean) * rstd * g3[kch] + bt3[kch];
      ov[jj] = (f16)gelu_exact(v);
    }
    *(f16x8*)(ts + r * 512 + ((g * 32) ^ ((r & 7) << 4))) = *(f16x8*)&ov[0];
    *(f16x8*)(ts + r * 512 + ((g * 32 + 16) ^ ((r & 7) << 4))) = *(f16x8*)&ov[8];
  }
  __syncthreads();
  // GEMM4: M=32 l, N=32, K=256. wave: mf=w&1 row-half, n4=w>>1 col-half
  const int mf = w & 1, n4 = w >> 1;
  f32x4 a4 = ZERO4;
#pragma unroll
  for (int ks = 0; ks < 8; ++ks) {
    int ar = mf * 16 + mrow;
    f16x8 a = *(const f16x8*)(ts + ar * 512 + (((ks << 6) + (kg << 4)) ^ ((ar & 7) << 4)));
    int br = n4 * 16 + mrow;
    f16x8 bb = *(const f16x8*)(w4t + br * 512 + (((ks << 6) + (kg << 4)) ^ ((br & 7) << 4)));
    a4 = __builtin_amdgcn_mfma_f32_16x16x32_f16(a, bb, a4, 0, 0, 0);
  }
  const int col = n4 * 16 + mrow;  // 0..31
#pragma unroll
  for (int i = 0; i < 4; ++i) {
    const int row = mf * 16 + kg * 4 + i;
    const int l = l0 + row;
    float adj = tanhf(a4[i] + b4[col]) * 0.02f;
    float padj = __shfl_xor(adj, 1, 64);
    if ((lane & 1) == 0) {
      const int n = col >> 1;
      const float2 offv = *(const float2*)(offset + (((b << 9) + l) << 5) + col);
      const float pos0v = tanhf(offv.x + adj);
      const float ref_y = ((float)n + 0.5f) * ((float)l + 1e-9f) * (1.0f / 4096.0f) - 1.0f;
      const float pos1v = tanhf(offv.y + padj + ref_y);
      *(float2*)(off_out + (((b << 9) + l) << 5) + col) = offv;
      *(float2*)(pos_out + (((b << 9) + l) << 5) + col) = make_float2(pos0v, pos1v);
    }
  }
}

// ---------------------------------------------------------------- K4
__global__ __launch_bounds__(256) void k4_gather(
    const float* __restrict__ x, const float* __restrict__ pos,
    float* __restrict__ outbuf) {
  const unsigned u = blockIdx.x * 256u + threadIdx.x;
  const unsigned t_idx = u >> 6;
  const unsigned cj = u & 63;
  const int b = t_idx >> 13;
  const int l = (t_idx >> 4) & 511;
  const float pos1 = pos[t_idx * 2 + 1];
  const float pix = (pos1 + 1.0f) * 0.5f * 511.0f;
  const float i0f = floorf(pix);
  const int i0 = (int)i0f;
  const float frac = pix - i0f;
  const int i1 = i0 + 1;
  const bool v0 = (i0 >= 0) && (i0 < 512) && (i0 <= l);
  const bool v1 = (i1 >= 0) && (i1 < 512) && (i1 <= l);
  const int c0 = i0 < 0 ? 0 : (i0 > 511 ? 511 : i0);
  const int c1 = i1 < 0 ? 0 : (i1 > 511 ? 511 : i1);
  const float w0  = v0 ? (1.0f - frac) : 0.0f;
  const float w1v = v1 ? frac : 0.0f;
  const float4* x4 = (const float4*)x;
  const float4 va = x4[(unsigned)((b << 9) + c0) * 64u + cj];
  const float4 vb = x4[(unsigned)((b << 9) + c1) * 64u + cj];
  float4 o;
  o.x = w0 * va.x + w1v * vb.x;
  o.y = w0 * va.y + w1v * vb.y;
  o.z = w0 * va.z + w1v * vb.z;
  o.w = w0 * va.w + w1v * vb.w;
  ((float4*)outbuf)[u] = o;
}

extern "C" void kernel_launch(void* const* d_in, const int* in_sizes, int n_in,
                              void* d_out, int out_size, void* d_ws, size_t ws_size,
                              hipStream_t stream) {
  const float* query  = (const float*)d_in[0];
  const float* x      = (const float*)d_in[1];
  const float* offset = (const float*)d_in[2];
  const float* w1  = (const float*)d_in[3];
  const float* b1  = (const float*)d_in[4];
  const float* g1  = (const float*)d_in[5];
  const float* bt1 = (const float*)d_in[6];
  const float* w2  = (const float*)d_in[7];
  const float* b2  = (const float*)d_in[8];
  const float* w3  = (const float*)d_in[9];
  const float* b3  = (const float*)d_in[10];
  const float* g3  = (const float*)d_in[11];
  const float* bt3 = (const float*)d_in[12];
  const float* w4  = (const float*)d_in[13];
  const float* b4  = (const float*)d_in[14];

  float* out     = (float*)d_out;                    // [B,L,N,C] = 67,108,864 f32
  float* off_out = out + 67108864;                   // [B,L,2N]
  float* pos_out = off_out + 524288;                 // [B,L,N,2]

  f16* wsbase = (f16*)d_ws;
  f16* w1T = wsbase;                                 // [128][512]
  f16* w2T = w1T + 65536;                            // [512][128]
  f16* w3T = w2T + 65536;                            // [256][256]
  f16* w4T = w3T + 65536;                            // [32][256]
  f16* t1  = w4T + 8192;                             // [32][256][128]
  f16* q   = t1 + 1048576;                           // [32][512][256]

  k0_prep<<<52, 256, 0, stream>>>(w1, w2, w3, w4, w1T, w2T, w3T, w4T);
  k1_gemm1<<<512, 256, 0, stream>>>(query, w1T, b1, g1, bt1, t1);
  k2_gemm2<<<1024, 256, 0, stream>>>(w2T, t1, b2, q);
  k3_adjust<<<512, 256, 0, stream>>>(q, w3T, b3, g3, bt3, w4T, b4, offset,
                                     off_out, pos_out);
  k4_gather<<<65536, 256, 0, stream>>>(x, pos_out, out);
}